// Round 1
// baseline (619.307 us; speedup 1.0000x reference)
//
#include <hip/hip_runtime.h>
#include <hip/hip_bf16.h>

#define B_N    64
#define K_LEN  2000
#define D_DIM  512
#define NEG_INF (-3.402823466e38f)
#define EPS_C  1e-6f
#define INV_SCALE (1.0f/22.62741699796952f)   // 1/sqrt(512)

// -------- kernel 1: fused q/v projection per (b,branch); also zeroes cv ----
// stage1: q[a] = query[b]·Wq[:,a] + bq[a]
// stage2: v[d] = (Wk[d,:]·q)/scale ; c = (q·bk)/scale (+ r for mono)
__global__ __launch_bounds__(256) void proj_kernel(
    const float* __restrict__ query,
    const float* __restrict__ Wq_m, const float* __restrict__ bq_m,
    const float* __restrict__ Wq_c, const float* __restrict__ bq_c,
    const float* __restrict__ Wk_m, const float* __restrict__ bk_m,
    const float* __restrict__ Wk_c, const float* __restrict__ bk_c,
    const float* __restrict__ r,
    float* __restrict__ v_all, float* __restrict__ c_all,
    float* __restrict__ cv)
{
    const int b = blockIdx.x, br = blockIdx.y, t = threadIdx.x;
    // zero this batch's cv slice (cv_kernel accumulates atomically later;
    // proj -> energy -> scan -> cv stream order guarantees visibility)
    cv[(size_t)b*D_DIM + br*256 + t] = 0.f;

    const float* Wq = br ? Wq_c : Wq_m;
    const float* bq = br ? bq_c : bq_m;
    const float* Wk = br ? Wk_c : Wk_m;
    const float* bk = br ? bk_c : bk_m;
    __shared__ float qs[D_DIM];   // query vector
    __shared__ float qv[D_DIM];   // projected q
    __shared__ float red[256];
    for (int i = t; i < D_DIM; i += 256) qs[i] = query[(size_t)b*D_DIM + i];
    __syncthreads();
    // stage 1: column dot-products, 4 partial accumulators to break FMA chain
    for (int a = t; a < D_DIM; a += 256) {
        float a0 = 0.f, a1 = 0.f, a2 = 0.f, a3 = 0.f;
        #pragma unroll 4
        for (int d = 0; d < D_DIM; d += 4) {
            a0 = fmaf(qs[d+0], Wq[(size_t)(d+0)*D_DIM + a], a0);
            a1 = fmaf(qs[d+1], Wq[(size_t)(d+1)*D_DIM + a], a1);
            a2 = fmaf(qs[d+2], Wq[(size_t)(d+2)*D_DIM + a], a2);
            a3 = fmaf(qs[d+3], Wq[(size_t)(d+3)*D_DIM + a], a3);
        }
        qv[a] = (a0 + a1) + (a2 + a3) + bq[a];
    }
    __syncthreads();
    // stage 2: row dot-products (coalesced float4 within row)
    for (int d = t; d < D_DIM; d += 256) {
        const float4* row = (const float4*)(Wk + (size_t)d*D_DIM);
        const float4* q4 = (const float4*)qv;
        float acc = 0.f;
        #pragma unroll 4
        for (int a4 = 0; a4 < D_DIM/4; ++a4) {
            float4 w = row[a4], q = q4[a4];
            acc = fmaf(w.x, q.x, acc); acc = fmaf(w.y, q.y, acc);
            acc = fmaf(w.z, q.z, acc); acc = fmaf(w.w, q.w, acc);
        }
        v_all[((size_t)b*2 + br)*D_DIM + d] = acc * INV_SCALE;
    }
    float part = 0.f;
    for (int a = t; a < D_DIM; a += 256) part = fmaf(qv[a], bk[a], part);
    red[t] = part; __syncthreads();
    for (int s = 128; s; s >>= 1) { if (t < s) red[t] += red[t + s]; __syncthreads(); }
    if (t == 0) c_all[b*2 + br] = red[0] * INV_SCALE + (br ? 0.f : r[0]);
}

// -------- kernel 2: energies. 16 lanes per row, 4 rows per wave-iteration --
// Each lane owns a contiguous 128B segment of one row (8 float4 in flight),
// reduce is 4 shfl_xor steps shared across all 4 rows of the wave.
__global__ __launch_bounds__(256) void energy_kernel(
    const float* __restrict__ key, const int* __restrict__ mask,
    const float* __restrict__ v_all, const float* __restrict__ c_all,
    float* __restrict__ e_mono, float* __restrict__ e_c)
{
    const int b = blockIdx.x;
    const int kb0 = blockIdx.y * 100;          // 20 chunks * 100 = 2000
    const int lane = threadIdx.x & 63;
    const int wave = threadIdx.x >> 6;
    const int sub  = lane & 15;                // lane-within-row group
    const int rsub = lane >> 4;                // which of 4 concurrent rows

    const float4* vmb = (const float4*)(v_all + ((size_t)b*2 + 0)*D_DIM) + sub*8;
    const float4* vcb = (const float4*)(v_all + ((size_t)b*2 + 1)*D_DIM) + sub*8;
    float4 vm[8], vc[8];
    #pragma unroll
    for (int i = 0; i < 8; ++i) vm[i] = vmb[i];
    #pragma unroll
    for (int i = 0; i < 8; ++i) vc[i] = vcb[i];
    const float cm = c_all[b*2 + 0], cc = c_all[b*2 + 1];

    for (int kg = kb0 + wave*4; kg < kb0 + 100; kg += 16) {
        const int k = kg + rsub;               // this lane's row
        const float4* kr = (const float4*)(key + ((size_t)b*K_LEN + k)*D_DIM) + sub*8;
        float4 x[8];
        #pragma unroll
        for (int i = 0; i < 8; ++i) x[i] = kr[i];
        float dm = 0.f, dc = 0.f;
        #pragma unroll
        for (int i = 0; i < 8; ++i) {
            dm = fmaf(x[i].x, vm[i].x, dm); dm = fmaf(x[i].y, vm[i].y, dm);
            dm = fmaf(x[i].z, vm[i].z, dm); dm = fmaf(x[i].w, vm[i].w, dm);
            dc = fmaf(x[i].x, vc[i].x, dc); dc = fmaf(x[i].y, vc[i].y, dc);
            dc = fmaf(x[i].z, vc[i].z, dc); dc = fmaf(x[i].w, vc[i].w, dc);
        }
        #pragma unroll
        for (int off = 8; off; off >>= 1) {
            dm += __shfl_xor(dm, off);
            dc += __shfl_xor(dc, off);
        }
        if (sub == 0) {
            const size_t gk = (size_t)b*K_LEN + k;
            const bool mk = mask[gk] != 0;
            e_mono[gk] = mk ? dm + cm : NEG_INF;
            e_c[gk]    = mk ? dc + cc : NEG_INF;
        }
    }
}

// -------- kernel 3: per-batch scans -> alpha, beta (wave-shuffle scans) ----
__global__ __launch_bounds__(256) void scan_kernel(
    const float* __restrict__ e_mono_g, const float* __restrict__ e_c_g,
    const float* __restrict__ noise, const float* __restrict__ aw_prev,
    float* __restrict__ alpha_out, float* __restrict__ beta_out)
{
    const int b = blockIdx.x, t = threadIdx.x;
    const int lane = t & 63, wv = t >> 6;
    __shared__ float sal[2048];  // alpha
    __shared__ float sse[2048];  // e_c then sm_exp
    __shared__ float su[2048];   // alpha/denom
    __shared__ float wsA[4], wsB[4], wsM[4];

    const float* em = e_mono_g + (size_t)b*K_LEN;
    const float* ec = e_c_g   + (size_t)b*K_LEN;
    const float* nz = noise   + (size_t)b*K_LEN;
    const float* aw = aw_prev + (size_t)b*K_LEN;

    const int base = t*8;
    const bool inb = base < K_LEN;            // K_LEN % 8 == 0: all-8 in/out
    float emv[8], nzv[8], ecv[8], awv[8];
    if (inb) {
        float4 a0 = ((const float4*)(em + base))[0], a1 = ((const float4*)(em + base))[1];
        emv[0]=a0.x; emv[1]=a0.y; emv[2]=a0.z; emv[3]=a0.w;
        emv[4]=a1.x; emv[5]=a1.y; emv[6]=a1.z; emv[7]=a1.w;
        float4 n0 = ((const float4*)(nz + base))[0], n1 = ((const float4*)(nz + base))[1];
        nzv[0]=n0.x; nzv[1]=n0.y; nzv[2]=n0.z; nzv[3]=n0.w;
        nzv[4]=n1.x; nzv[5]=n1.y; nzv[6]=n1.z; nzv[7]=n1.w;
        float4 c0 = ((const float4*)(ec + base))[0], c1 = ((const float4*)(ec + base))[1];
        ecv[0]=c0.x; ecv[1]=c0.y; ecv[2]=c0.z; ecv[3]=c0.w;
        ecv[4]=c1.x; ecv[5]=c1.y; ecv[6]=c1.z; ecv[7]=c1.w;
        float4 w0 = ((const float4*)(aw + base))[0], w1 = ((const float4*)(aw + base))[1];
        awv[0]=w0.x; awv[1]=w0.y; awv[2]=w0.z; awv[3]=w0.w;
        awv[4]=w1.x; awv[5]=w1.y; awv[6]=w1.z; awv[7]=w1.w;
    } else {
        #pragma unroll
        for (int j = 0; j < 8; ++j) { emv[j]=0.f; nzv[j]=0.f; ecv[j]=NEG_INF; awv[j]=0.f; }
    }

    float p[8], lg[8];
    #pragma unroll
    for (int j = 0; j < 8; ++j) {
        float pv = 0.f, lv = 0.f;
        if (inb) {
            float e = emv[j] + nzv[j];               // NOISE_STD = 1
            pv = 1.f / (1.f + expf(-e));
            float om = fminf(fmaxf(1.f - pv, EPS_C), 1.f);
            lv = logf(om);
        }
        p[j] = pv; lg[j] = lv;
        sse[base + j] = inb ? ecv[j] : NEG_INF;
    }

    // ---- scan 1: exclusive cumsum of log(1-p) ----
    float ex[8]; float run = 0.f;
    #pragma unroll
    for (int j = 0; j < 8; ++j) { ex[j] = run; run += lg[j]; }
    float incl = run;
    #pragma unroll
    for (int off = 1; off < 64; off <<= 1) {
        float v = __shfl_up(incl, off, 64);
        if (lane >= off) incl += v;
    }
    if (lane == 63) wsA[wv] = incl;
    __syncthreads();                                         // (1)
    float wpre = 0.f;
    #pragma unroll
    for (int w = 0; w < 4; ++w) if (w < wv) wpre += wsA[w];
    const float pre = wpre + incl - run;                     // thread-exclusive

    // cp + scan 2 input
    float cp_[8], t2i[8]; float run2 = 0.f;
    #pragma unroll
    for (int j = 0; j < 8; ++j) {
        float c = expf(pre + ex[j]);
        cp_[j] = c;
        float t2 = inb ? awv[j] / fminf(fmaxf(c, EPS_C), 1.f) : 0.f;
        run2 += t2; t2i[j] = run2;                           // thread-inclusive
    }
    float incl2 = run2;
    #pragma unroll
    for (int off = 1; off < 64; off <<= 1) {
        float v = __shfl_up(incl2, off, 64);
        if (lane >= off) incl2 += v;
    }
    if (lane == 63) wsB[wv] = incl2;
    __syncthreads();                                         // (2)
    float wpre2 = 0.f;
    #pragma unroll
    for (int w = 0; w < 4; ++w) if (w < wv) wpre2 += wsB[w];
    const float pre2 = wpre2 + incl2 - run2;

    float al[8];
    #pragma unroll
    for (int j = 0; j < 8; ++j) {
        al[j] = p[j] * cp_[j] * (pre2 + t2i[j]);
        sal[base + j] = al[j];
    }
    if (inb) {
        float* ao = alpha_out + (size_t)b*K_LEN + base;
        ((float4*)ao)[0] = make_float4(al[0], al[1], al[2], al[3]);
        ((float4*)ao)[1] = make_float4(al[4], al[5], al[6], al[7]);
    }
    __syncthreads();                                         // (3) sse+sal done

    // ---- max over e_c ----
    float mx = NEG_INF;
    for (int k = t; k < 2048; k += 256) mx = fmaxf(mx, sse[k]);
    #pragma unroll
    for (int off = 32; off; off >>= 1) mx = fmaxf(mx, __shfl_xor(mx, off));
    if (lane == 0) wsM[wv] = mx;
    __syncthreads();                                         // (4)
    mx = fmaxf(fmaxf(wsM[0], wsM[1]), fmaxf(wsM[2], wsM[3]));

    for (int k = t; k < 2048; k += 256) {
        float se = 0.f;
        if (k < K_LEN) se = fmaxf(expf(sse[k] - mx), 1e-5f);
        sse[k] = se;
    }
    __syncthreads();                                         // (5)
    // denom = moving_sum(sm_exp, back=7, fwd=0); u = alpha/denom
    for (int k = t; k < 2048; k += 256) {
        float u = 0.f;
        if (k < K_LEN) {
            float den = 0.f;
            int j0 = (k > 7) ? (k - 7) : 0;
            for (int j = j0; j <= k; ++j) den += sse[j];
            u = sal[k] / den;                                // SHARP = 1
        }
        su[k] = u;
    }
    __syncthreads();                                         // (6)
    // beta = sm_exp * moving_sum(u, back=0, fwd=7)
    for (int k = t; k < K_LEN; k += 256) {
        float s2 = 0.f;
        #pragma unroll
        for (int j = 0; j < 8; ++j) s2 += su[k + j];
        beta_out[(size_t)b*K_LEN + k] = sse[k] * s2;
    }
}

// -------- kernel 4: cv, one pass over value, atomic accumulate ------------
__global__ __launch_bounds__(256) void cv_kernel(
    const float* __restrict__ value, const float* __restrict__ beta,
    float* __restrict__ cv)
{
    const int b = blockIdx.x, s = blockIdx.y, t = threadIdx.x;
    const int f4 = t & 127, half = t >> 7;
    const int k0 = s * 100;
    __shared__ float bs[100];
    __shared__ float4 comb[128];
    if (t < 100) bs[t] = beta[(size_t)b*K_LEN + k0 + t];
    __syncthreads();
    float4 acc = {0.f, 0.f, 0.f, 0.f};
    for (int k = k0 + half; k < k0 + 100; k += 2) {
        float4 vv = ((const float4*)(value + ((size_t)b*K_LEN + k)*D_DIM))[f4];
        float bb = bs[k - k0];
        acc.x = fmaf(bb, vv.x, acc.x); acc.y = fmaf(bb, vv.y, acc.y);
        acc.z = fmaf(bb, vv.z, acc.z); acc.w = fmaf(bb, vv.w, acc.w);
    }
    if (half) comb[f4] = acc;
    __syncthreads();
    if (!half) {
        float4 o = comb[f4];
        float* dst = cv + (size_t)b*D_DIM + f4*4;
        atomicAdd(dst + 0, acc.x + o.x);
        atomicAdd(dst + 1, acc.y + o.y);
        atomicAdd(dst + 2, acc.z + o.z);
        atomicAdd(dst + 3, acc.w + o.w);
    }
}

extern "C" void kernel_launch(void* const* d_in, const int* in_sizes, int n_in,
                              void* d_out, int out_size, void* d_ws, size_t ws_size,
                              hipStream_t stream) {
    const float* key     = (const float*)d_in[0];
    const float* value   = (const float*)d_in[1];
    const float* query   = (const float*)d_in[2];
    const int*   mask    = (const int*)d_in[3];
    const float* aw_prev = (const float*)d_in[4];
    const float* noise   = (const float*)d_in[5];
    const float* Wk_m    = (const float*)d_in[6];
    const float* bk_m    = (const float*)d_in[7];
    const float* Wq_m    = (const float*)d_in[8];
    const float* bq_m    = (const float*)d_in[9];
    const float* r       = (const float*)d_in[10];
    const float* Wk_c    = (const float*)d_in[11];
    const float* bk_c    = (const float*)d_in[12];
    const float* Wq_c    = (const float*)d_in[13];
    const float* bq_c    = (const float*)d_in[14];

    float* out   = (float*)d_out;
    float* cv    = out;                       // [64,1,512] = 32768
    float* alpha = out + (size_t)B_N*D_DIM;   // [64,2000]  = 128000

    float* ws      = (float*)d_ws;
    float* e_mono  = ws;                  // 128000
    float* e_c     = ws + 128000;         // 128000
    float* beta    = ws + 256000;         // 128000
    float* v_all   = ws + 384000;         // 65536
    float* c_all   = ws + 449536;         // 128

    proj_kernel<<<dim3(B_N, 2), 256, 0, stream>>>(query, Wq_m, bq_m, Wq_c, bq_c,
                                                  Wk_m, bk_m, Wk_c, bk_c, r,
                                                  v_all, c_all, cv);
    energy_kernel<<<dim3(B_N, 20), 256, 0, stream>>>(key, mask, v_all, c_all, e_mono, e_c);
    scan_kernel<<<B_N, 256, 0, stream>>>(e_mono, e_c, noise, aw_prev, alpha, beta);
    cv_kernel<<<dim3(B_N, 20), 256, 0, stream>>>(value, beta, cv);
}